// Round 1
// baseline (2714.410 us; speedup 1.0000x reference)
//
#include <hip/hip_runtime.h>
#include <stdint.h>

#define NPTS 2048
#define KDIM 4096

typedef __bf16 bf16x8 __attribute__((ext_vector_type(8)));
typedef float f32x4 __attribute__((ext_vector_type(4)));

__device__ __forceinline__ unsigned short f2bf(float f) {
    unsigned int u = __float_as_uint(f);
    u = (u + 0x7FFFu + ((u >> 16) & 1u)) >> 16;   // round-to-nearest-even
    return (unsigned short)u;
}

// ---------------- Kernel 1: row squared norms (fp32 exact) ----------------
__global__ __launch_bounds__(256) void sqnorm_kernel(const float* __restrict__ x,
                                                     float* __restrict__ sq) {
    const int row = blockIdx.x;
    const float* xr = x + (size_t)row * KDIM;
    const int t = threadIdx.x;
    float s = 0.f;
    #pragma unroll
    for (int i = 0; i < 4; ++i) {
        int c = t * 4 + i * 1024;
        float4 v = *(const float4*)(xr + c);
        s += v.x * v.x + v.y * v.y + v.z * v.z + v.w * v.w;
    }
    for (int off = 32; off; off >>= 1) s += __shfl_down(s, off);
    __shared__ float p[4];
    if ((t & 63) == 0) p[t >> 6] = s;
    __syncthreads();
    if (t == 0) sq[row] = p[0] + p[1] + p[2] + p[3];
}

// ---------------- Kernel 2: D2 = sq_i + sq_j - 2 * X X^T (bf16 MFMA) ------
// 128x128 tile per block, 256 threads = 4 waves (2x2), each wave 4x4 MFMA tiles.
#define BM 128
#define BK 32
#define LDS_S 40   // LDS row stride in bf16 elements: 80B rows -> 16B aligned, 2-way bank aliasing (free)

__global__ __launch_bounds__(256) void gemm_d2_kernel(const float* __restrict__ x,
                                                      const float* __restrict__ sq,
                                                      float* __restrict__ D2) {
    __shared__ unsigned short As[BM * LDS_S];
    __shared__ unsigned short Bs[BM * LDS_S];
    const int I0 = blockIdx.y * BM;
    const int J0 = blockIdx.x * BM;
    const int t = threadIdx.x;
    const int lane = t & 63;
    const int w = t >> 6;
    const int wr = w >> 1, wc = w & 1;
    const int m = lane & 15, q = lane >> 4;

    f32x4 acc[4][4] = {};

    for (int kc = 0; kc < KDIM; kc += BK) {
        // stage 128 rows x 32 floats per tile, converting fp32->bf16 into LDS
        #pragma unroll
        for (int s = 0; s < 4; ++s) {
            int unit = t + 256 * s;          // 1024 float4-units per tile
            int r = unit >> 3, c = unit & 7; // c: float4 index within the 32-float row chunk
            float4 va = *(const float4*)(x + (size_t)(I0 + r) * KDIM + kc + c * 4);
            float4 vb = *(const float4*)(x + (size_t)(J0 + r) * KDIM + kc + c * 4);
            uint2 ua, ub;
            ua.x = (unsigned)f2bf(va.x) | ((unsigned)f2bf(va.y) << 16);
            ua.y = (unsigned)f2bf(va.z) | ((unsigned)f2bf(va.w) << 16);
            ub.x = (unsigned)f2bf(vb.x) | ((unsigned)f2bf(vb.y) << 16);
            ub.y = (unsigned)f2bf(vb.z) | ((unsigned)f2bf(vb.w) << 16);
            *(uint2*)(&As[r * LDS_S + c * 4]) = ua;
            *(uint2*)(&Bs[r * LDS_S + c * 4]) = ub;
        }
        __syncthreads();
        bf16x8 af[4], bg[4];
        #pragma unroll
        for (int rt = 0; rt < 4; ++rt)
            af[rt] = *(const bf16x8*)(&As[(wr * 64 + rt * 16 + m) * LDS_S + q * 8]);
        #pragma unroll
        for (int ct = 0; ct < 4; ++ct)
            bg[ct] = *(const bf16x8*)(&Bs[(wc * 64 + ct * 16 + m) * LDS_S + q * 8]);
        #pragma unroll
        for (int rt = 0; rt < 4; ++rt)
            #pragma unroll
            for (int ct = 0; ct < 4; ++ct)
                acc[rt][ct] = __builtin_amdgcn_mfma_f32_16x16x32_bf16(
                    af[rt], bg[ct], acc[rt][ct], 0, 0, 0);
        __syncthreads();
    }

    // epilogue: C/D layout col = lane&15, row = (lane>>4)*4 + reg  [m89/m91-verified]
    #pragma unroll
    for (int rt = 0; rt < 4; ++rt) {
        #pragma unroll
        for (int ct = 0; ct < 4; ++ct) {
            #pragma unroll
            for (int r = 0; r < 4; ++r) {
                int i = I0 + wr * 64 + rt * 16 + q * 4 + r;
                int j = J0 + wc * 64 + ct * 16 + m;
                float v = sq[i] + sq[j] - 2.0f * acc[rt][ct][r];
                if (i == j) v = __builtin_inff();  // self-edges never selectable
                D2[(size_t)i * NPTS + j] = v;
            }
        }
    }
}

// ---------------- Kernel 3: single-block Prim MST + bitonic sort ----------
// Output = MST edge weights sorted ascending = Kruskal emission order.
__global__ __launch_bounds__(1024) void prim_sort_kernel(const float* __restrict__ D2,
                                                         float* __restrict__ out) {
    __shared__ float wlist[NPTS];
    __shared__ float red_v[16];
    __shared__ int   red_i[16];
    __shared__ int   s_u;
    const int t = threadIdx.x;
    const int lane = t & 63, wv = t >> 6;
    const int v0 = 2 * t, v1 = 2 * t + 1;
    float d0 = __builtin_inff(), d1 = __builtin_inff();
    bool in0 = (v0 == 0), in1 = false;
    int u = 0;

    for (int it = 0; it < NPTS - 1; ++it) {
        // update min-dist-to-tree with the newly added vertex's row (coalesced 8B/thread)
        float2 r = *(const float2*)(D2 + (size_t)u * NPTS + v0);
        d0 = fminf(d0, r.x);
        d1 = fminf(d1, r.y);
        if (in0) d0 = __builtin_inff();
        if (in1) d1 = __builtin_inff();
        float mv; int mi;
        if (d0 <= d1) { mv = d0; mi = v0; } else { mv = d1; mi = v1; }
        // wave argmin
        for (int off = 32; off; off >>= 1) {
            float ov = __shfl_down(mv, off);
            int   oi = __shfl_down(mi, off);
            if (ov < mv) { mv = ov; mi = oi; }
        }
        if (lane == 0) { red_v[wv] = mv; red_i[wv] = mi; }
        __syncthreads();
        if (t < 64) {  // wave 0 reduces the 16 wave partials
            float mv2 = (lane < 16) ? red_v[lane] : __builtin_inff();
            int   mi2 = (lane < 16) ? red_i[lane] : 0;
            for (int off = 8; off; off >>= 1) {
                float ov = __shfl_down(mv2, off);
                int   oi = __shfl_down(mi2, off);
                if (ov < mv2) { mv2 = ov; mi2 = oi; }
            }
            if (t == 0) { s_u = mi2; wlist[it] = mv2; }
        }
        __syncthreads();
        u = s_u;
        if (v0 == u) in0 = true;
        if (v1 == u) in1 = true;
    }

    __syncthreads();
    if (t == 0) wlist[NPTS - 1] = __builtin_inff();  // pad (2047 real edges)
    __syncthreads();

    // bitonic sort ascending over 2048 elements, 1024 threads
    for (int k = 2; k <= NPTS; k <<= 1) {
        for (int j = k >> 1; j > 0; j >>= 1) {
            for (int i = t; i < NPTS; i += 1024) {
                int l = i ^ j;
                if (l > i) {
                    float a = wlist[i], b = wlist[l];
                    bool up = ((i & k) == 0);
                    if ((a > b) == up) { wlist[i] = b; wlist[l] = a; }
                }
            }
            __syncthreads();
        }
    }

    for (int i = t; i < NPTS - 1; i += 1024)
        out[i] = sqrtf(fmaxf(wlist[i], 0.0f));
}

extern "C" void kernel_launch(void* const* d_in, const int* in_sizes, int n_in,
                              void* d_out, int out_size, void* d_ws, size_t ws_size,
                              hipStream_t stream) {
    const float* x = (const float*)d_in[0];
    float* out = (float*)d_out;
    float* sq  = (float*)d_ws;                       // 2048 * 4 B
    float* D2  = (float*)((char*)d_ws + 8192);       // 2048*2048*4 = 16 MB

    hipLaunchKernelGGL(sqnorm_kernel, dim3(NPTS), dim3(256), 0, stream, x, sq);
    hipLaunchKernelGGL(gemm_d2_kernel, dim3(16, 16), dim3(256), 0, stream, x, sq, D2);
    hipLaunchKernelGGL(prim_sort_kernel, dim3(1), dim3(1024), 0, stream, D2, out);
}

// Round 2
// 317.650 us; speedup vs baseline: 8.5453x; 8.5453x over previous
//
#include <hip/hip_runtime.h>
#include <stdint.h>

#define NPTS 2048
#define KDIM 4096
#define INVALID_KEY 0xFFFFFFFFFFFFFFFFull

typedef __bf16 bf16x8 __attribute__((ext_vector_type(8)));
typedef float f32x4 __attribute__((ext_vector_type(4)));

__device__ __forceinline__ unsigned short f2bf(float f) {
    unsigned int u = __float_as_uint(f);
    u = (u + 0x7FFFu + ((u >> 16) & 1u)) >> 16;   // round-to-nearest-even
    return (unsigned short)u;
}

// ---------------- Kernel 1: row squared norms (fp32 exact) ----------------
__global__ __launch_bounds__(256) void sqnorm_kernel(const float* __restrict__ x,
                                                     float* __restrict__ sq) {
    const int row = blockIdx.x;
    const float* xr = x + (size_t)row * KDIM;
    const int t = threadIdx.x;
    float s = 0.f;
    #pragma unroll
    for (int i = 0; i < 4; ++i) {
        int c = t * 4 + i * 1024;
        float4 v = *(const float4*)(xr + c);
        s += v.x * v.x + v.y * v.y + v.z * v.z + v.w * v.w;
    }
    for (int off = 32; off; off >>= 1) s += __shfl_down(s, off);
    __shared__ float p[4];
    if ((t & 63) == 0) p[t >> 6] = s;
    __syncthreads();
    if (t == 0) sq[row] = p[0] + p[1] + p[2] + p[3];
}

// ---------------- Kernel 2: D2 = sq_i + sq_j - 2 * X X^T (bf16 MFMA) ------
#define BM 128
#define BK 32
#define LDS_S 40

__global__ __launch_bounds__(256) void gemm_d2_kernel(const float* __restrict__ x,
                                                      const float* __restrict__ sq,
                                                      float* __restrict__ D2) {
    __shared__ unsigned short As[BM * LDS_S];
    __shared__ unsigned short Bs[BM * LDS_S];
    const int I0 = blockIdx.y * BM;
    const int J0 = blockIdx.x * BM;
    const int t = threadIdx.x;
    const int lane = t & 63;
    const int w = t >> 6;
    const int wr = w >> 1, wc = w & 1;
    const int m = lane & 15, q = lane >> 4;

    f32x4 acc[4][4] = {};

    for (int kc = 0; kc < KDIM; kc += BK) {
        #pragma unroll
        for (int s = 0; s < 4; ++s) {
            int unit = t + 256 * s;
            int r = unit >> 3, c = unit & 7;
            float4 va = *(const float4*)(x + (size_t)(I0 + r) * KDIM + kc + c * 4);
            float4 vb = *(const float4*)(x + (size_t)(J0 + r) * KDIM + kc + c * 4);
            uint2 ua, ub;
            ua.x = (unsigned)f2bf(va.x) | ((unsigned)f2bf(va.y) << 16);
            ua.y = (unsigned)f2bf(va.z) | ((unsigned)f2bf(va.w) << 16);
            ub.x = (unsigned)f2bf(vb.x) | ((unsigned)f2bf(vb.y) << 16);
            ub.y = (unsigned)f2bf(vb.z) | ((unsigned)f2bf(vb.w) << 16);
            *(uint2*)(&As[r * LDS_S + c * 4]) = ua;
            *(uint2*)(&Bs[r * LDS_S + c * 4]) = ub;
        }
        __syncthreads();
        bf16x8 af[4], bg[4];
        #pragma unroll
        for (int rt = 0; rt < 4; ++rt)
            af[rt] = *(const bf16x8*)(&As[(wr * 64 + rt * 16 + m) * LDS_S + q * 8]);
        #pragma unroll
        for (int ct = 0; ct < 4; ++ct)
            bg[ct] = *(const bf16x8*)(&Bs[(wc * 64 + ct * 16 + m) * LDS_S + q * 8]);
        #pragma unroll
        for (int rt = 0; rt < 4; ++rt)
            #pragma unroll
            for (int ct = 0; ct < 4; ++ct)
                acc[rt][ct] = __builtin_amdgcn_mfma_f32_16x16x32_bf16(
                    af[rt], bg[ct], acc[rt][ct], 0, 0, 0);
        __syncthreads();
    }

    #pragma unroll
    for (int rt = 0; rt < 4; ++rt) {
        #pragma unroll
        for (int ct = 0; ct < 4; ++ct) {
            #pragma unroll
            for (int r = 0; r < 4; ++r) {
                int i = I0 + wr * 64 + rt * 16 + q * 4 + r;
                int j = J0 + wc * 64 + ct * 16 + m;
                float v = sq[i] + sq[j] - 2.0f * acc[rt][ct][r];
                v = (i == j) ? __builtin_inff() : fmaxf(v, 0.0f);  // clamp: keys need non-negative floats
                D2[(size_t)i * NPTS + j] = v;
            }
        }
    }
}

// ---------------- Kernel 3: init Borůvka state ----------------------------
__global__ __launch_bounds__(1024) void boruvka_init(int* __restrict__ comp,
                                                     int* __restrict__ ctl) {
    const int t = threadIdx.x;
    comp[t] = t;
    comp[t + 1024] = t + 1024;
    if (t == 0) { ctl[0] = 0; ctl[1] = 0; }  // ecnt, done
}

// ---------------- Kernel 4: per-vertex min outgoing edge ------------------
// One wave per vertex. Key = (w_bits<<22) | (min(v,j)<<11) | max(v,j):
// undirected-edge-unique total order => hooking cycles are only mutual 2-cycles.
__global__ __launch_bounds__(256) void boruvka_minedge(const float* __restrict__ D2,
                                                       const int* __restrict__ comp,
                                                       unsigned long long* __restrict__ cand,
                                                       const int* __restrict__ ctl) {
    if (ctl[1]) return;
    __shared__ int cs[NPTS];
    const int t = threadIdx.x;
    #pragma unroll
    for (int k = 0; k < 2; ++k)
        *(int4*)(cs + t * 4 + k * 1024) = *(const int4*)(comp + t * 4 + k * 1024);
    __syncthreads();
    const int lane = t & 63, wv = t >> 6;
    const int v = blockIdx.x * 4 + wv;
    const int mc = cs[v];
    const float* row = D2 + (size_t)v * NPTS;
    unsigned long long best = INVALID_KEY;
    #pragma unroll
    for (int k = 0; k < 8; ++k) {
        int j0 = k * 256 + lane * 4;
        float4 w4 = *(const float4*)(row + j0);
        int4 c4 = *(const int4*)(cs + j0);
        float wa[4] = {w4.x, w4.y, w4.z, w4.w};
        int ca[4] = {c4.x, c4.y, c4.z, c4.w};
        #pragma unroll
        for (int e = 0; e < 4; ++e) {
            if (ca[e] != mc) {
                int j = j0 + e;
                unsigned long long a = (v < j) ? v : j;
                unsigned long long b = (v < j) ? j : v;
                unsigned long long key =
                    ((unsigned long long)__float_as_uint(wa[e]) << 22) | (a << 11) | b;
                best = (key < best) ? key : best;
            }
        }
    }
    for (int off = 32; off; off >>= 1) {
        unsigned long long o = __shfl_down(best, off);
        best = (o < best) ? o : best;
    }
    if (lane == 0) cand[v] = best;
}

// ---------------- Kernel 5: component reduce + hook + compress ------------
__global__ __launch_bounds__(1024) void boruvka_merge(const unsigned long long* __restrict__ cand,
                                                      int* __restrict__ comp,
                                                      float* __restrict__ ew,
                                                      int* __restrict__ ctl) {
    if (ctl[1]) return;
    __shared__ unsigned long long best[NPTS];
    __shared__ int par[NPTS];
    __shared__ int sc[NPTS];
    __shared__ int nroots;
    const int t = threadIdx.x;
    for (int c = t; c < NPTS; c += 1024) { best[c] = INVALID_KEY; sc[c] = comp[c]; }
    if (t == 0) nroots = 0;
    __syncthreads();
    for (int v = t; v < NPTS; v += 1024) {
        unsigned long long k = cand[v];
        if (k != INVALID_KEY) atomicMin(&best[sc[v]], k);
    }
    __syncthreads();
    for (int c = t; c < NPTS; c += 1024) {
        int p = c;
        if (sc[c] == c && best[c] != INVALID_KEY) {
            unsigned long long k = best[c];
            int a = (int)((k >> 11) & 2047);
            int b = (int)(k & 2047);
            int j = (sc[a] == c) ? b : a;       // endpoint outside component c
            int rj = sc[j];
            // mutual selection <=> identical key (keys are unique per undirected edge)
            bool mutual = (best[rj] == k);
            if (!(mutual && c < rj)) {          // smaller root survives a 2-cycle
                p = rj;
                ew[atomicAdd(&ctl[0], 1)] = __uint_as_float((unsigned)(k >> 22));
            }
        }
        par[c] = p;
    }
    __syncthreads();
    // pointer jumping (depth <= #components, 11 doublings cover 2048)
    for (int it = 0; it < 11; ++it) {
        for (int c = t; c < NPTS; c += 1024) {
            int p = par[c];
            par[c] = par[p];   // benign race: any value read is a valid ancestor
        }
        __syncthreads();
    }
    for (int v = t; v < NPTS; v += 1024) {
        int nc = par[sc[v]];
        comp[v] = nc;
        if (v == nc) atomicAdd(&nroots, 1);
    }
    __syncthreads();
    if (t == 0 && nroots == 1) ctl[1] = 1;
}

// ---------------- Kernel 6: sort 2047 weights asc, sqrt, write out --------
__global__ __launch_bounds__(1024) void sort_out_kernel(const float* __restrict__ ew,
                                                        float* __restrict__ out) {
    __shared__ float wl[NPTS];
    const int t = threadIdx.x;
    for (int i = t; i < NPTS; i += 1024)
        wl[i] = (i < NPTS - 1) ? ew[i] : __builtin_inff();
    __syncthreads();
    for (int k = 2; k <= NPTS; k <<= 1) {
        for (int j = k >> 1; j > 0; j >>= 1) {
            for (int i = t; i < NPTS; i += 1024) {
                int l = i ^ j;
                if (l > i) {
                    float a = wl[i], b = wl[l];
                    bool up = ((i & k) == 0);
                    if ((a > b) == up) { wl[i] = b; wl[l] = a; }
                }
            }
            __syncthreads();
        }
    }
    for (int i = t; i < NPTS - 1; i += 1024)
        out[i] = sqrtf(fmaxf(wl[i], 0.0f));
}

extern "C" void kernel_launch(void* const* d_in, const int* in_sizes, int n_in,
                              void* d_out, int out_size, void* d_ws, size_t ws_size,
                              hipStream_t stream) {
    const float* x = (const float*)d_in[0];
    float* out = (float*)d_out;
    char* ws = (char*)d_ws;
    float* sq   = (float*)ws;                               // 8 KB
    float* D2   = (float*)(ws + 8192);                      // 16 MB
    int*   comp = (int*)(ws + 8192 + 16777216);             // 8 KB
    unsigned long long* cand = (unsigned long long*)(ws + 8192 + 16777216 + 8192);  // 16 KB
    float* ew   = (float*)(ws + 8192 + 16777216 + 8192 + 16384);                    // 8 KB
    int*   ctl  = (int*)(ws + 8192 + 16777216 + 8192 + 16384 + 8192);               // ecnt, done

    hipLaunchKernelGGL(sqnorm_kernel, dim3(NPTS), dim3(256), 0, stream, x, sq);
    hipLaunchKernelGGL(gemm_d2_kernel, dim3(16, 16), dim3(256), 0, stream, x, sq, D2);
    hipLaunchKernelGGL(boruvka_init, dim3(1), dim3(1024), 0, stream, comp, ctl);
    for (int r = 0; r < 11; ++r) {
        hipLaunchKernelGGL(boruvka_minedge, dim3(NPTS / 4), dim3(256), 0, stream,
                           D2, comp, cand, ctl);
        hipLaunchKernelGGL(boruvka_merge, dim3(1), dim3(1024), 0, stream,
                           cand, comp, ew, ctl);
    }
    hipLaunchKernelGGL(sort_out_kernel, dim3(1), dim3(1024), 0, stream, ew, out);
}

// Round 3
// 233.883 us; speedup vs baseline: 11.6058x; 1.3582x over previous
//
#include <hip/hip_runtime.h>
#include <stdint.h>

#define NPTS 2048
#define KDIM 4096
#define INVALID_KEY 0xFFFFFFFFFFFFFFFFull

typedef __bf16 bf16x8 __attribute__((ext_vector_type(8)));
typedef float f32x4 __attribute__((ext_vector_type(4)));

__device__ __forceinline__ unsigned short f2bf(float f) {
    unsigned int u = __float_as_uint(f);
    u = (u + 0x7FFFu + ((u >> 16) & 1u)) >> 16;   // round-to-nearest-even
    return (unsigned short)u;
}

__device__ __forceinline__ void gld_lds16(const unsigned short* g, unsigned short* l) {
    __builtin_amdgcn_global_load_lds(
        (const __attribute__((address_space(1))) unsigned int*)g,
        (__attribute__((address_space(3))) unsigned int*)l, 16, 0, 0);
}

// ---- Kernel 1: fused fp32->bf16 convert + row squared norms (fp32) -------
__global__ __launch_bounds__(256) void convert_sqnorm_kernel(const float* __restrict__ x,
                                                             unsigned short* __restrict__ xb,
                                                             float* __restrict__ sq) {
    const int row = blockIdx.x;
    const float* xr = x + (size_t)row * KDIM;
    unsigned short* xbr = xb + (size_t)row * KDIM;
    const int t = threadIdx.x;
    float s = 0.f;
    #pragma unroll
    for (int k = 0; k < 4; ++k) {
        int c = t * 4 + k * 1024;
        float4 v = *(const float4*)(xr + c);
        s += v.x * v.x + v.y * v.y + v.z * v.z + v.w * v.w;
        uint2 u;
        u.x = (unsigned)f2bf(v.x) | ((unsigned)f2bf(v.y) << 16);
        u.y = (unsigned)f2bf(v.z) | ((unsigned)f2bf(v.w) << 16);
        *(uint2*)(xbr + c) = u;
    }
    for (int off = 32; off; off >>= 1) s += __shfl_down(s, off);
    __shared__ float p[4];
    if ((t & 63) == 0) p[t >> 6] = s;
    __syncthreads();
    if (t == 0) sq[row] = p[0] + p[1] + p[2] + p[3];
}

// ---- Kernel 2: D2 = sq_i + sq_j - 2 * Xb Xb^T (bf16 MFMA, gLDS staging) --
// 64(M) x 128(N) tile, 256 threads = 4 waves; wave w computes all 64 rows x
// cols [w*32, w*32+32). Unpadded 64B LDS rows (gLDS constraint). 512 blocks
// -> 2 blocks/CU for cross-block barrier overlap.
#define BK 32

__global__ __launch_bounds__(256, 2) void gemm_d2_glds(const unsigned short* __restrict__ xb,
                                                       const float* __restrict__ sq,
                                                       float* __restrict__ D2) {
    __shared__ unsigned short As[64 * 32];    // 4 KB
    __shared__ unsigned short Bs[128 * 32];   // 8 KB
    const int I0 = blockIdx.y * 64;
    const int J0 = blockIdx.x * 128;
    const int t = threadIdx.x;
    const int lane = t & 63;
    const int w = t >> 6;
    const int m = lane & 15, q = lane >> 4;
    const int srow = t >> 2, sseg = t & 3;    // staging: 16B unit per thread

    const unsigned short* gA = xb + (size_t)(I0 + srow) * KDIM + sseg * 8;
    const unsigned short* gB0 = xb + (size_t)(J0 + srow) * KDIM + sseg * 8;
    const unsigned short* gB1 = xb + (size_t)(J0 + 64 + srow) * KDIM + sseg * 8;
    unsigned short* lA = &As[w * 512];               // wave-uniform base; HW adds lane*16
    unsigned short* lB0 = &Bs[w * 512];
    unsigned short* lB1 = &Bs[2048 + w * 512];

    f32x4 acc[4][2] = {};

    for (int kc = 0; kc < KDIM; kc += BK) {
        gld_lds16(gA + kc, lA);
        gld_lds16(gB0 + kc, lB0);
        gld_lds16(gB1 + kc, lB1);
        __syncthreads();   // drains vmcnt -> LDS visible

        bf16x8 af[4], bg[2];
        #pragma unroll
        for (int rt = 0; rt < 4; ++rt)
            af[rt] = *(const bf16x8*)(&As[(rt * 16 + m) * 32 + q * 8]);
        #pragma unroll
        for (int ct = 0; ct < 2; ++ct)
            bg[ct] = *(const bf16x8*)(&Bs[(w * 32 + ct * 16 + m) * 32 + q * 8]);
        #pragma unroll
        for (int rt = 0; rt < 4; ++rt)
            #pragma unroll
            for (int ct = 0; ct < 2; ++ct)
                acc[rt][ct] = __builtin_amdgcn_mfma_f32_16x16x32_bf16(
                    af[rt], bg[ct], acc[rt][ct], 0, 0, 0);
        __syncthreads();
    }

    // C/D layout: col = lane&15 (m), row = q*4 + reg  [m89/m91-verified]
    #pragma unroll
    for (int rt = 0; rt < 4; ++rt) {
        #pragma unroll
        for (int ct = 0; ct < 2; ++ct) {
            #pragma unroll
            for (int r = 0; r < 4; ++r) {
                int i = I0 + rt * 16 + q * 4 + r;
                int j = J0 + w * 32 + ct * 16 + m;
                float v = sq[i] + sq[j] - 2.0f * acc[rt][ct][r];
                v = (i == j) ? __builtin_inff() : fmaxf(v, 0.0f);
                D2[(size_t)i * NPTS + j] = v;
            }
        }
    }
}

// ---------------- Kernel 3: init Borůvka state ----------------------------
__global__ __launch_bounds__(1024) void boruvka_init(int* __restrict__ comp,
                                                     int* __restrict__ ctl) {
    const int t = threadIdx.x;
    comp[t] = t;
    comp[t + 1024] = t + 1024;
    if (t == 0) { ctl[0] = 0; ctl[1] = 0; }  // ecnt, done
}

// ---------------- Kernel 4: per-vertex min outgoing edge ------------------
// Key = (w_bits<<22) | (min(v,j)<<11) | max(v,j): undirected-edge-unique
// total order => hooking cycles are only mutual 2-cycles.
__global__ __launch_bounds__(256) void boruvka_minedge(const float* __restrict__ D2,
                                                       const int* __restrict__ comp,
                                                       unsigned long long* __restrict__ cand,
                                                       const int* __restrict__ ctl) {
    if (ctl[1]) return;
    __shared__ int cs[NPTS];
    const int t = threadIdx.x;
    #pragma unroll
    for (int k = 0; k < 2; ++k)
        *(int4*)(cs + t * 4 + k * 1024) = *(const int4*)(comp + t * 4 + k * 1024);
    __syncthreads();
    const int lane = t & 63, wv = t >> 6;
    const int v = blockIdx.x * 4 + wv;
    const int mc = cs[v];
    const float* row = D2 + (size_t)v * NPTS;
    unsigned long long best = INVALID_KEY;
    #pragma unroll
    for (int k = 0; k < 8; ++k) {
        int j0 = k * 256 + lane * 4;
        float4 w4 = *(const float4*)(row + j0);
        int4 c4 = *(const int4*)(cs + j0);
        float wa[4] = {w4.x, w4.y, w4.z, w4.w};
        int ca[4] = {c4.x, c4.y, c4.z, c4.w};
        #pragma unroll
        for (int e = 0; e < 4; ++e) {
            if (ca[e] != mc) {
                int j = j0 + e;
                unsigned long long a = (v < j) ? v : j;
                unsigned long long b = (v < j) ? j : v;
                unsigned long long key =
                    ((unsigned long long)__float_as_uint(wa[e]) << 22) | (a << 11) | b;
                best = (key < best) ? key : best;
            }
        }
    }
    for (int off = 32; off; off >>= 1) {
        unsigned long long o = __shfl_down(best, off);
        best = (o < best) ? o : best;
    }
    if (lane == 0) cand[v] = best;
}

// ---------------- Kernel 5: component reduce + hook + compress ------------
__global__ __launch_bounds__(1024) void boruvka_merge(const unsigned long long* __restrict__ cand,
                                                      int* __restrict__ comp,
                                                      float* __restrict__ ew,
                                                      int* __restrict__ ctl) {
    if (ctl[1]) return;
    __shared__ unsigned long long best[NPTS];
    __shared__ int par[NPTS];
    __shared__ int sc[NPTS];
    __shared__ int nroots;
    const int t = threadIdx.x;
    for (int c = t; c < NPTS; c += 1024) { best[c] = INVALID_KEY; sc[c] = comp[c]; }
    if (t == 0) nroots = 0;
    __syncthreads();
    for (int v = t; v < NPTS; v += 1024) {
        unsigned long long k = cand[v];
        if (k != INVALID_KEY) atomicMin(&best[sc[v]], k);
    }
    __syncthreads();
    for (int c = t; c < NPTS; c += 1024) {
        int p = c;
        if (sc[c] == c && best[c] != INVALID_KEY) {
            unsigned long long k = best[c];
            int a = (int)((k >> 11) & 2047);
            int b = (int)(k & 2047);
            int j = (sc[a] == c) ? b : a;       // endpoint outside component c
            int rj = sc[j];
            bool mutual = (best[rj] == k);      // keys unique per undirected edge
            if (!(mutual && c < rj)) {          // smaller root survives a 2-cycle
                p = rj;
                ew[atomicAdd(&ctl[0], 1)] = __uint_as_float((unsigned)(k >> 22));
            }
        }
        par[c] = p;
    }
    __syncthreads();
    for (int it = 0; it < 11; ++it) {
        for (int c = t; c < NPTS; c += 1024) {
            int p = par[c];
            par[c] = par[p];   // benign race: any read value is a valid ancestor
        }
        __syncthreads();
    }
    for (int v = t; v < NPTS; v += 1024) {
        int nc = par[sc[v]];
        comp[v] = nc;
        if (v == nc) atomicAdd(&nroots, 1);
    }
    __syncthreads();
    if (t == 0 && nroots == 1) ctl[1] = 1;
}

// ---------------- Kernel 6: sort 2047 weights asc, sqrt, write out --------
__global__ __launch_bounds__(1024) void sort_out_kernel(const float* __restrict__ ew,
                                                        float* __restrict__ out) {
    __shared__ float wl[NPTS];
    const int t = threadIdx.x;
    for (int i = t; i < NPTS; i += 1024)
        wl[i] = (i < NPTS - 1) ? ew[i] : __builtin_inff();
    __syncthreads();
    for (int k = 2; k <= NPTS; k <<= 1) {
        for (int j = k >> 1; j > 0; j >>= 1) {
            for (int i = t; i < NPTS; i += 1024) {
                int l = i ^ j;
                if (l > i) {
                    float a = wl[i], b = wl[l];
                    bool up = ((i & k) == 0);
                    if ((a > b) == up) { wl[i] = b; wl[l] = a; }
                }
            }
            __syncthreads();
        }
    }
    for (int i = t; i < NPTS - 1; i += 1024)
        out[i] = sqrtf(fmaxf(wl[i], 0.0f));
}

extern "C" void kernel_launch(void* const* d_in, const int* in_sizes, int n_in,
                              void* d_out, int out_size, void* d_ws, size_t ws_size,
                              hipStream_t stream) {
    const float* x = (const float*)d_in[0];
    float* out = (float*)d_out;
    char* ws = (char*)d_ws;
    unsigned short* xb = (unsigned short*)ws;                   // 16 MB bf16 X
    float* D2   = (float*)(ws + 16777216);                      // 16 MB
    float* sq   = (float*)(ws + 2 * 16777216);                  // 8 KB
    int*   comp = (int*)(ws + 2 * 16777216 + 8192);             // 8 KB
    unsigned long long* cand = (unsigned long long*)(ws + 2 * 16777216 + 16384);  // 16 KB
    float* ew   = (float*)(ws + 2 * 16777216 + 32768);          // 8 KB
    int*   ctl  = (int*)(ws + 2 * 16777216 + 40960);            // ecnt, done

    hipLaunchKernelGGL(convert_sqnorm_kernel, dim3(NPTS), dim3(256), 0, stream, x, xb, sq);
    hipLaunchKernelGGL(gemm_d2_glds, dim3(16, 32), dim3(256), 0, stream, xb, sq, D2);
    hipLaunchKernelGGL(boruvka_init, dim3(1), dim3(1024), 0, stream, comp, ctl);
    for (int r = 0; r < 11; ++r) {
        hipLaunchKernelGGL(boruvka_minedge, dim3(NPTS / 4), dim3(256), 0, stream,
                           D2, comp, cand, ctl);
        hipLaunchKernelGGL(boruvka_merge, dim3(1), dim3(1024), 0, stream,
                           cand, comp, ew, ctl);
    }
    hipLaunchKernelGGL(sort_out_kernel, dim3(1), dim3(1024), 0, stream, ew, out);
}